// Round 5
// baseline (245.369 us; speedup 1.0000x reference)
//
#include <hip/hip_runtime.h>

#define S_LEN 2048
#define EMB   1024
#define NH    16
#define HD    64
#define BS    2
#define QSCALE 0.18033688f   // 0.125 * log2(e): folded into Q so attn uses exp2 directly

typedef __bf16 bf16;
typedef bf16  bf16x8 __attribute__((ext_vector_type(8)));
typedef bf16  bf16x4 __attribute__((ext_vector_type(4)));
typedef float f32x4  __attribute__((ext_vector_type(4)));
typedef unsigned long long u64;
typedef unsigned int u32;

__device__ __forceinline__ bf16x8 ld8(const bf16* p){ return *(const bf16x8*)p; }

// async global->LDS, 16B/lane; LDS dest = wave-uniform base + lane*16
__device__ __forceinline__ void gl_lds16(const bf16* g, void* l) {
    __builtin_amdgcn_global_load_lds(
        (const __attribute__((address_space(1))) void*)g,
        (__attribute__((address_space(3))) void*)l,
        16, 0, 0);
}

// XOR swizzle: 16B groups within a 128B row
#define SW(row, g) ((((g) ^ ((row) & 7))) * 8)

// ---------------------------------------------------------------------------
// mask int32 [B*S, S] -> bits [B*S, S/64] u64.
// ---------------------------------------------------------------------------
__global__ __launch_bounds__(256)
void pack_mask(const int* __restrict__ mask, u64* __restrict__ pm)
{
    int lane = threadIdx.x & 63;
    int row  = blockIdx.x * 4 + (threadIdx.x >> 6);
    const int* mr = mask + (size_t)row * S_LEN;
    u64* pr = pm + (size_t)row * (S_LEN / 64);
    for (int i = 0; i < S_LEN / 64; ++i) {
        u64 bits = __ballot(mr[i * 64 + lane] != 0);
        if (lane == 0) pr[i] = bits;
    }
}

// ---------------------------------------------------------------------------
// Weights fp32 -> bf16 transposed Wt[z][n][k]; z in {q,k,v,o}; z<3 per-head.
// ---------------------------------------------------------------------------
__global__ __launch_bounds__(256)
void transpose_w(const float* __restrict__ W0, const float* __restrict__ W1,
                 const float* __restrict__ W2, const float* __restrict__ W3,
                 bf16* __restrict__ Wt)
{
    const int z = blockIdx.z;
    const float* W = z == 0 ? W0 : z == 1 ? W1 : z == 2 ? W2 : W3;
    const bool head = z < 3;
    const int k0 = blockIdx.x * 64, n0 = blockIdx.y * 64;
    const int tid = threadIdx.x;
    __shared__ float T[64][68];
    {
        int k = k0 + (tid >> 2), cg = (tid & 3) * 16;
        size_t base = head ? ((size_t)(n0 >> 6) * ((size_t)EMB * HD) + (size_t)k * HD + cg)
                           : ((size_t)k * EMB + n0 + cg);
        #pragma unroll
        for (int g = 0; g < 4; ++g) {
            f32x4 v = *(const f32x4*)(W + base + g * 4);
            #pragma unroll
            for (int j = 0; j < 4; ++j) T[tid >> 2][cg + g * 4 + j] = v[j];
        }
    }
    __syncthreads();
    {
        int n = n0 + (tid >> 2), ck = (tid & 3) * 16;
        bf16 t16[16];
        #pragma unroll
        for (int j = 0; j < 16; ++j) t16[j] = (bf16)T[ck + j][tid >> 2];
        bf16* outp = Wt + (size_t)z * EMB * EMB + (size_t)n * EMB + k0 + ck;
        *(bf16x8*)outp       = *(bf16x8*)t16;
        *(bf16x8*)(outp + 8) = *(bf16x8*)(t16 + 8);
    }
}

// ---------------------------------------------------------------------------
// x fp32 -> bf16
// ---------------------------------------------------------------------------
__global__ __launch_bounds__(256)
void cvt_f32_bf16(const float* __restrict__ x, bf16* __restrict__ y)
{
    size_t i = ((size_t)blockIdx.x * 256 + threadIdx.x) * 16;
    bf16 t[16];
    #pragma unroll
    for (int g = 0; g < 4; ++g) {
        f32x4 v = *(const f32x4*)(x + i + g * 4);
        #pragma unroll
        for (int j = 0; j < 4; ++j) t[g * 4 + j] = (bf16)v[j];
    }
    *(bf16x8*)(y + i)     = *(bf16x8*)t;
    *(bf16x8*)(y + i + 8) = *(bf16x8*)(t + 8);
}

// ---------------------------------------------------------------------------
// scale Q in-place by QSCALE (fallback paths)
// ---------------------------------------------------------------------------
__global__ __launch_bounds__(256)
void scale_q(bf16* __restrict__ q)
{
    size_t i = ((size_t)blockIdx.x * 256 + threadIdx.x) * 8;
    bf16x8 v = *(bf16x8*)(q + i);
    #pragma unroll
    for (int j = 0; j < 8; ++j) v[j] = (bf16)((float)v[j] * QSCALE);
    *(bf16x8*)(q + i) = v;
}

// ---------------------------------------------------------------------------
// Fused QKV GEMM, m97 structure: 256 thr, tile 128x128, BK=64, 2x2 waves,
// 4x4 acc, global_load_lds staging. Epilogue routes z = n0>>10:
//   z=0 Q (bias + QSCALE fold), z=1 K natural, z=2 V^T scatter.
// ---------------------------------------------------------------------------
__global__ __launch_bounds__(256, 3)
void gemm_qkv(const void* __restrict__ Ap, const bf16* __restrict__ Wt,
              const float* __restrict__ bqp, const float* __restrict__ bkp,
              const float* __restrict__ bvp,
              bf16* __restrict__ qb, bf16* __restrict__ kb, bf16* __restrict__ VT,
              int a32)
{
    const int tid  = threadIdx.x;
    const int lane = tid & 63, quad = lane >> 4, c = lane & 15;
    const int w = tid >> 6, wm = w >> 1, wn = w & 1;
    const int m0 = blockIdx.x * 128;
    const int n0 = blockIdx.y * 128;          // [0, 3072)

    __shared__ bf16 Ash[128][64];
    __shared__ bf16 Wsh[128][64];

    f32x4 acc[4][4];
    #pragma unroll
    for (int mt = 0; mt < 4; ++mt)
        #pragma unroll
        for (int nt = 0; nt < 4; ++nt) acc[mt][nt] = (f32x4){0.f,0.f,0.f,0.f};

    const int lrow = lane >> 3, lcol = (lane & 7) * 8;

    for (int k0 = 0; k0 < EMB; k0 += 64) {
        __syncthreads();
        if (!a32) {
            const bf16* A = (const bf16*)Ap;
            #pragma unroll
            for (int j = 0; j < 4; ++j)
                gl_lds16(A + (size_t)(m0 + w * 32 + j * 8 + lrow) * EMB + k0 + lcol,
                         &Ash[w * 32 + j * 8][0]);
        } else {
            const float* A = (const float*)Ap + (size_t)(m0 + (tid >> 1)) * EMB + k0 + (tid & 1) * 32;
            bf16 t[32];
            #pragma unroll
            for (int g = 0; g < 8; ++g) {
                f32x4 v = *(const f32x4*)(A + g * 4);
                #pragma unroll
                for (int j = 0; j < 4; ++j) t[g * 4 + j] = (bf16)v[j];
            }
            #pragma unroll
            for (int g2 = 0; g2 < 4; ++g2)
                *(bf16x8*)&Ash[tid >> 1][(tid & 1) * 32 + g2 * 8] = *(bf16x8*)(t + g2 * 8);
        }
        #pragma unroll
        for (int j = 0; j < 4; ++j)
            gl_lds16(Wt + (size_t)(n0 + w * 32 + j * 8 + lrow) * EMB + k0 + lcol,
                     &Wsh[w * 32 + j * 8][0]);
        __syncthreads();

        #pragma unroll
        for (int kh = 0; kh < 2; ++kh) {
            bf16x8 af[4], bfv[4];
            #pragma unroll
            for (int mt = 0; mt < 4; ++mt) af[mt]  = ld8(&Ash[wm * 64 + mt * 16 + c][kh * 32 + quad * 8]);
            #pragma unroll
            for (int nt = 0; nt < 4; ++nt) bfv[nt] = ld8(&Wsh[wn * 64 + nt * 16 + c][kh * 32 + quad * 8]);
            #pragma unroll
            for (int mt = 0; mt < 4; ++mt)
                #pragma unroll
                for (int nt = 0; nt < 4; ++nt)
                    acc[mt][nt] = __builtin_amdgcn_mfma_f32_16x16x32_bf16(af[mt], bfv[nt], acc[mt][nt], 0, 0, 0);
        }
    }

    const int z = n0 >> 10;   // block-uniform
    const float* bias = z == 0 ? bqp : z == 1 ? bkp : bvp;
    #pragma unroll
    for (int nt = 0; nt < 4; ++nt) {
        int nn = (n0 & 1023) + wn * 64 + nt * 16 + c;
        float bv_ = bias[nn];
        #pragma unroll
        for (int mt = 0; mt < 4; ++mt)
            #pragma unroll
            for (int r = 0; r < 4; ++r) {
                int m = m0 + wm * 64 + mt * 16 + quad * 4 + r;
                float v = acc[mt][nt][r] + bv_;
                if (z == 0)      qb[(size_t)m * EMB + nn] = (bf16)(v * QSCALE);
                else if (z == 1) kb[(size_t)m * EMB + nn] = (bf16)v;
                else {
                    int head = nn >> 6, d = nn & 63;
                    VT[((size_t)((m >> 11) * NH + head) * HD + d) * S_LEN + (m & 2047)] = (bf16)v;
                }
            }
    }
}

// ---------------------------------------------------------------------------
// Out-projection: 128x128 tile (clone of verified gemm_qkv structure,
// a32=0 path, fp32 epilogue). Grid (32, 8).
// ---------------------------------------------------------------------------
__global__ __launch_bounds__(256, 3)
void gemm_o(const bf16* __restrict__ Ap, const bf16* __restrict__ Wt,
            const float* __restrict__ bo, float* __restrict__ C)
{
    const int tid  = threadIdx.x;
    const int lane = tid & 63, quad = lane >> 4, c = lane & 15;
    const int w = tid >> 6, wm = w >> 1, wn = w & 1;
    const int m0 = blockIdx.x * 128;
    const int n0 = blockIdx.y * 128;

    __shared__ bf16 Ash[128][64];
    __shared__ bf16 Wsh[128][64];

    f32x4 acc[4][4];
    #pragma unroll
    for (int mt = 0; mt < 4; ++mt)
        #pragma unroll
        for (int nt = 0; nt < 4; ++nt) acc[mt][nt] = (f32x4){0.f,0.f,0.f,0.f};

    const int lrow = lane >> 3, lcol = (lane & 7) * 8;

    for (int k0 = 0; k0 < EMB; k0 += 64) {
        __syncthreads();
        #pragma unroll
        for (int j = 0; j < 4; ++j)
            gl_lds16(Ap + (size_t)(m0 + w * 32 + j * 8 + lrow) * EMB + k0 + lcol,
                     &Ash[w * 32 + j * 8][0]);
        #pragma unroll
        for (int j = 0; j < 4; ++j)
            gl_lds16(Wt + (size_t)(n0 + w * 32 + j * 8 + lrow) * EMB + k0 + lcol,
                     &Wsh[w * 32 + j * 8][0]);
        __syncthreads();

        #pragma unroll
        for (int kh = 0; kh < 2; ++kh) {
            bf16x8 af[4], bfv[4];
            #pragma unroll
            for (int mt = 0; mt < 4; ++mt) af[mt]  = ld8(&Ash[wm * 64 + mt * 16 + c][kh * 32 + quad * 8]);
            #pragma unroll
            for (int nt = 0; nt < 4; ++nt) bfv[nt] = ld8(&Wsh[wn * 64 + nt * 16 + c][kh * 32 + quad * 8]);
            #pragma unroll
            for (int mt = 0; mt < 4; ++mt)
                #pragma unroll
                for (int nt = 0; nt < 4; ++nt)
                    acc[mt][nt] = __builtin_amdgcn_mfma_f32_16x16x32_bf16(af[mt], bfv[nt], acc[mt][nt], 0, 0, 0);
        }
    }

    #pragma unroll
    for (int nt = 0; nt < 4; ++nt) {
        int n = n0 + wn * 64 + nt * 16 + c;
        float bv_ = bo[n];
        #pragma unroll
        for (int mt = 0; mt < 4; ++mt)
            #pragma unroll
            for (int r = 0; r < 4; ++r) {
                int m = m0 + wm * 64 + mt * 16 + quad * 4 + r;
                C[(size_t)m * EMB + n] = acc[mt][nt][r] + bv_;
            }
    }
}

// ---------------------------------------------------------------------------
// Fallback GEMM (R7, verified): 128x128 tile, 512 thr, register staging.
// ---------------------------------------------------------------------------
__global__ __launch_bounds__(512)
void gemm128(const void* __restrict__ Ap, const float* __restrict__ Wp,
             const bf16* __restrict__ Wtp, const float* __restrict__ bias,
             void* __restrict__ Cp, int N, int K, int whead,
             int m_base, int a32, int cmode)
{
    const int tid  = threadIdx.x;
    const int lane = tid & 63, quad = lane >> 4, c = lane & 15;
    const int w = tid >> 6, wm = w >> 2, wn = w & 3;
    const int m0 = blockIdx.x * 128, n0 = blockIdx.y * 128;

    __shared__ bf16 Ash[128][64];
    __shared__ bf16 Wsh[128][64];

    f32x4 acc[4][2];
    #pragma unroll
    for (int mt = 0; mt < 4; ++mt)
        #pragma unroll
        for (int nt = 0; nt < 2; ++nt) acc[mt][nt] = (f32x4){0.f,0.f,0.f,0.f};

    const int arow = tid >> 2, aq = tid & 3;

    auto compute = [&]() {
        #pragma unroll
        for (int kh = 0; kh < 2; ++kh) {
            bf16x8 bfr[2];
            #pragma unroll
            for (int nt = 0; nt < 2; ++nt) {
                int rw = wn * 32 + nt * 16 + c;
                bfr[nt] = ld8(&Wsh[rw][SW(rw, kh * 4 + quad)]);
            }
            #pragma unroll
            for (int mt = 0; mt < 4; ++mt) {
                int ra = wm * 64 + mt * 16 + c;
                bf16x8 af = ld8(&Ash[ra][SW(ra, kh * 4 + quad)]);
                #pragma unroll
                for (int nt = 0; nt < 2; ++nt)
                    acc[mt][nt] = __builtin_amdgcn_mfma_f32_16x16x32_bf16(af, bfr[nt], acc[mt][nt], 0, 0, 0);
            }
        }
    };

    for (int k0 = 0; k0 < K; k0 += 64) {
        __syncthreads();
        if (a32) {
            const float* A = (const float*)Ap + (size_t)(m_base + m0 + arow) * K + k0 + aq * 16;
            bf16 t16[16];
            #pragma unroll
            for (int g = 0; g < 4; ++g) {
                f32x4 v = *(const f32x4*)(A + g * 4);
                #pragma unroll
                for (int j = 0; j < 4; ++j) t16[g * 4 + j] = (bf16)v[j];
            }
            *(bf16x8*)&Ash[arow][SW(arow, aq * 2)]     = *(bf16x8*)t16;
            *(bf16x8*)&Ash[arow][SW(arow, aq * 2 + 1)] = *(bf16x8*)(t16 + 8);
        } else {
            const bf16* A = (const bf16*)Ap + (size_t)(m_base + m0 + arow) * K + k0 + aq * 16;
            *(bf16x8*)&Ash[arow][SW(arow, aq * 2)]     = ld8(A);
            *(bf16x8*)&Ash[arow][SW(arow, aq * 2 + 1)] = ld8(A + 8);
        }
        {
            int nl = tid & 127, kg = tid >> 7;
            int n = n0 + nl;
            size_t base    = whead ? ((size_t)(n >> 6) * ((size_t)K * HD) + (n & 63))
                                   : (size_t)n;
            size_t kstride = whead ? (size_t)HD : (size_t)N;
            #pragma unroll
            for (int p = 0; p < 2; ++p) {
                int grp = kg + 4 * p;
                bf16 t8[8];
                #pragma unroll
                for (int j = 0; j < 8; ++j)
                    t8[j] = (bf16)Wp[base + (size_t)(k0 + grp * 8 + j) * kstride];
                *(bf16x8*)&Wsh[nl][SW(nl, grp)] = *(bf16x8*)t8;
            }
        }
        __syncthreads();
        compute();
    }

    #pragma unroll
    for (int nt = 0; nt < 2; ++nt) {
        int n = n0 + wn * 32 + nt * 16 + c;
        float bv_ = bias[n];
        #pragma unroll
        for (int mt = 0; mt < 4; ++mt)
            #pragma unroll
            for (int r = 0; r < 4; ++r) {
                int m = m0 + wm * 64 + mt * 16 + quad * 4 + r;
                float v = acc[mt][nt][r] + bv_;
                if (cmode == 0)      ((bf16*)Cp)[(size_t)m * N + n] = (bf16)v;
                else if (cmode == 1) ((float*)Cp)[(size_t)m * N + n] = v;
                else {
                    int mm = m_base + m;
                    ((bf16*)Cp)[((size_t)((mm >> 11) * NH + (n >> 6)) * HD + (n & 63)) * S_LEN + (mm & 2047)] = (bf16)v;
                }
            }
    }
}

// ---------------------------------------------------------------------------
// Flash attention, S^T orientation. 512 thr = 8 waves, q-tile 128, XCD remap.
// R5 change: 2x4 wave tiling. Wave w = (kw=w>>2, qw=w&3) computes
// S^T [32 keys][32 q] and O^T [32 d][32 q] (kw doubles as d-half in PV).
// K/V^T fragment reads are shared across the wave's 2 q-subtiles:
// per-wave-chunk b128 reads 18 -> 12 (K 8->4, V 8->4, P 2->4). The R4
// counters put the LDS read pipe at ~75% of chunk time (288 KB/CU/chunk at
// ~85 B/cyc) -> this cuts the dominant term 33%. P is now cross-wave:
// shared Psh[128 q][64 k] (same SW swizzle / b64-write / b128-read pattern
// as the proven per-wave Psh) + a second __syncthreads per chunk.
// l needs a kw-pair reduction -> tiny Lsh epilogue. loadKV issued after
// barrier B so its drain is free and HBM/L2 latency hides under PV.
// ---------------------------------------------------------------------------
__global__ __launch_bounds__(512, 2)
void attn_kernel(bf16* q0p, bf16* q1p, const bf16* __restrict__ kbuf,
                 const bf16* __restrict__ VTg, const u64* __restrict__ pmask)
{
    const int tid  = threadIdx.x;
    const int w    = tid >> 6;          // 0..7
    const int lane = tid & 63;
    const int quad = lane >> 4;
    const int c    = lane & 15;
    const int qw   = w & 3;             // 32-q block within the 128-q tile
    const int kw   = w >> 2;            // key-half (QK^T) / d-half (PV)
    // XCD-chunked bijective remap (gridDim = 16 x 32 = 512 blocks)
    const int flat  = blockIdx.y * 16 + blockIdx.x;
    const int flat2 = (flat & 7) * 64 + (flat >> 3);
    const int q0   = (flat2 & 15) * 128;
    const int bh   = flat2 >> 4;
    const int b    = bh >> 4, h = bh & 15;

    bf16* qc = b ? q1p : q0p;
    const bf16* kh_ = kbuf + (size_t)b * S_LEN * EMB + h * HD;
    const bf16* vt  = VTg + (size_t)bh * HD * S_LEN;

    __shared__ bf16 Ksh [2][64][64];
    __shared__ bf16 VTsh[2][64][64];
    __shared__ bf16 Psh[128][64];          // P^T as [q][k], SW-swizzled
    __shared__ float Lsh[2][4][2][16];     // [kw][qw][rq][c] partial l

    // Q fragments (B-operand): wave owns rows q0 + qw*32 + rq*16 + c
    bf16x8 qf[2][2];
    #pragma unroll
    for (int rq = 0; rq < 2; ++rq)
        #pragma unroll
        for (int kk = 0; kk < 2; ++kk)
            qf[rq][kk] = ld8(qc + (size_t)(q0 + qw * 32 + rq * 16 + c) * EMB + h * HD + kk * 32 + quad * 8);

    const u64* pmr0 = pmask + (size_t)(b * S_LEN + q0 + qw * 32 + c) * (S_LEN / 64);
    const u64* pmr1 = pmr0 + (size_t)16 * (S_LEN / 64);

    float l2[2] = {0.f, 0.f};
    f32x4 o[2][2];                         // [dt][rq]
    #pragma unroll
    for (int dt = 0; dt < 2; ++dt)
        #pragma unroll
        for (int rq = 0; rq < 2; ++rq) o[dt][rq] = (f32x4){0.f,0.f,0.f,0.f};

    const int srow = tid >> 3, sg = tid & 7;   // 64 rows x 8 groups
    bf16x8 kr, vr;
    auto loadKV = [&](int t0) {
        kr = ld8(kh_ + (size_t)(t0 + srow) * EMB + sg * 8);
        vr = ld8(vt + (size_t)srow * S_LEN + t0 + sg * 8);
    };

    loadKV(0);
    int buf = 0;
    for (int t0 = 0; t0 < S_LEN; t0 += 64) {
        *(bf16x8*)&Ksh [buf][srow][SW(srow, sg)] = kr;
        *(bf16x8*)&VTsh[buf][srow][SW(srow, sg)] = vr;
        __syncthreads();                       // A: stage -> compute

        u64 pm0 = pmr0[t0 >> 6], pm1 = pmr1[t0 >> 6];
        u32 h0 = (u32)(pm0 >> (kw * 32 + quad * 4));
        u32 h1 = (u32)(pm1 >> (kw * 32 + quad * 4));

        // S^T[32k x 32q] = K-half . Q^T : K frags shared across rq
        f32x4 sc[2][2];                    // [tt][rq]
        #pragma unroll
        for (int tt = 0; tt < 2; ++tt)
            #pragma unroll
            for (int rq = 0; rq < 2; ++rq) sc[tt][rq] = (f32x4){0.f,0.f,0.f,0.f};
        #pragma unroll
        for (int tt = 0; tt < 2; ++tt)
            #pragma unroll
            for (int kk = 0; kk < 2; ++kk) {
                int rk = kw * 32 + tt * 16 + c;
                bf16x8 ka = ld8(&Ksh[buf][rk][SW(rk, kk * 4 + quad)]);
                #pragma unroll
                for (int rq = 0; rq < 2; ++rq)
                    sc[tt][rq] = __builtin_amdgcn_mfma_f32_16x16x32_bf16(ka, qf[rq][kk], sc[tt][rq], 0, 0, 0);
            }

        // softmax: p = mask ? exp2(s) : 0 ; write P^T[q][k] to shared Psh
        #pragma unroll
        for (int rq = 0; rq < 2; ++rq) {
            u32 hh = rq ? h1 : h0;
            int q = qw * 32 + rq * 16 + c;
            #pragma unroll
            for (int tt = 0; tt < 2; ++tt) {
                bf16x4 pv;
                #pragma unroll
                for (int r = 0; r < 4; ++r) {
                    float e = __builtin_amdgcn_exp2f(sc[tt][rq][r]);
                    e = ((hh >> (tt * 16 + r)) & 1) ? e : 0.f;
                    l2[rq] += e;
                    pv[r] = (bf16)e;
                }
                *(bf16x4*)&Psh[q][SW(q, kw * 4 + tt * 2 + (quad >> 1)) + (quad & 1) * 4] = pv;
            }
        }
        __syncthreads();                       // B: P producer -> consumer

        if (t0 + 64 < S_LEN) loadKV(t0 + 64);  // prefetch hides under PV

        // O^T[32d x 32q] += V^T-half . P^T : V frags shared across rq
        #pragma unroll
        for (int th = 0; th < 2; ++th) {
            bf16x8 pf[2];
            #pragma unroll
            for (int rq = 0; rq < 2; ++rq) {
                int q = qw * 32 + rq * 16 + c;
                pf[rq] = ld8(&Psh[q][SW(q, th * 4 + quad)]);
            }
            #pragma unroll
            for (int dt = 0; dt < 2; ++dt) {
                int rv = kw * 32 + dt * 16 + c;
                bf16x8 av = ld8(&VTsh[buf][rv][SW(rv, th * 4 + quad)]);
                #pragma unroll
                for (int rq = 0; rq < 2; ++rq)
                    o[dt][rq] = __builtin_amdgcn_mfma_f32_16x16x32_bf16(av, pf[rq], o[dt][rq], 0, 0, 0);
            }
        }
        buf ^= 1;
    }

    // epilogue: quad-reduce partial l, pair-sum across kw via Lsh, normalize
    float lr[2];
    #pragma unroll
    for (int rq = 0; rq < 2; ++rq) {
        float t = l2[rq];
        t += __shfl_xor(t, 16);
        t += __shfl_xor(t, 32);
        lr[rq] = t;
    }
    if (quad == 0) {
        Lsh[kw][qw][0][c] = lr[0];
        Lsh[kw][qw][1][c] = lr[1];
    }
    __syncthreads();
    #pragma unroll
    for (int rq = 0; rq < 2; ++rq) {
        float lt = Lsh[0][qw][rq][c] + Lsh[1][qw][rq][c];
        float inv = 1.0f / fmaxf(lt, 1e-30f);
        #pragma unroll
        for (int dt = 0; dt < 2; ++dt) {
            bf16x4 ov;
            #pragma unroll
            for (int r = 0; r < 4; ++r) ov[r] = (bf16)(o[dt][rq][r] * inv);
            *(bf16x4*)&qc[(size_t)(q0 + qw * 32 + rq * 16 + c) * EMB + h * HD + kw * 32 + dt * 16 + quad * 4] = ov;
        }
    }
}

// ---------------------------------------------------------------------------
// d_out: V^T [0:8MB) + K [8:16MB) (consumed by attn before fp32 out-proj).
// ---------------------------------------------------------------------------
extern "C" void kernel_launch(void* const* d_in, const int* in_sizes, int n_in,
                              void* d_out, int out_size, void* d_ws, size_t ws_size,
                              hipStream_t stream)
{
    const float* x    = (const float*)d_in[0];
    const int*   mask = (const int*)d_in[1];
    const float* Wq   = (const float*)d_in[2];
    const float* bq   = (const float*)d_in[3];
    const float* Wk   = (const float*)d_in[4];
    const float* bk   = (const float*)d_in[5];
    const float* Wv   = (const float*)d_in[6];
    const float* bv   = (const float*)d_in[7];
    const float* Wo   = (const float*)d_in[8];
    const float* bo   = (const float*)d_in[9];
    float* out = (float*)d_out;

    const size_t SLAB = (size_t)S_LEN * EMB;
    const size_t QB = (size_t)BS * SLAB * sizeof(bf16);          // 8 MB
    const size_t WT = (size_t)4 * EMB * EMB * sizeof(bf16);      // 8 MB
    const size_t PM = (size_t)BS * S_LEN * (S_LEN / 64) * 8;     // 1 MB
    const size_t XB = (size_t)BS * SLAB * sizeof(bf16);          // 8 MB

    bf16* VT = (bf16*)d_out;
    bf16* kb = (bf16*)d_out + BS * SLAB;

    dim3 b256(256), b512(512);
    dim3 gAtt (S_LEN / 128, BS * NH);
    dim3 gT   (EMB / 64, EMB / 64, 4);
    dim3 gPk  (BS * S_LEN / 4);
    dim3 gFull(BS * S_LEN / 128, EMB / 128);
    dim3 gHalf(S_LEN / 128, EMB / 128);

    if (ws_size >= QB + WT + PM + 64) {
        bf16* qb  = (bf16*)d_ws;
        bf16* Wt  = (bf16*)((char*)d_ws + QB);
        u64*  pm  = (u64*)((char*)d_ws + QB + WT);
        const void* xA = x; int a32 = 1;
        if (ws_size >= QB + WT + PM + XB + 64) {
            bf16* xbf = (bf16*)((char*)d_ws + QB + WT + PM);
            cvt_f32_bf16<<<dim3(1024), b256, 0, stream>>>(x, xbf);
            xA = xbf; a32 = 0;
        }
        pack_mask<<<gPk, b256, 0, stream>>>(mask, pm);
        transpose_w<<<gT, b256, 0, stream>>>(Wq, Wk, Wv, Wo, Wt);

        gemm_qkv<<<dim3(BS * S_LEN / 128, 3 * EMB / 128), b256, 0, stream>>>(
            xA, Wt, bq, bk, bv, qb, kb, VT, a32);

        attn_kernel<<<gAtt, b512, 0, stream>>>(qb, qb + SLAB, kb, VT, pm);

        gemm_o<<<dim3(BS * S_LEN / 128, EMB / 128), b256, 0, stream>>>(
            qb, Wt + (size_t)3 * EMB * EMB, bo, out);
    } else if (ws_size >= QB + PM + 64) {
        bf16* qb = (bf16*)d_ws;
        u64*  pm = (u64*)((char*)d_ws + QB);
        pack_mask<<<gPk, b256, 0, stream>>>(mask, pm);

        gemm128<<<gFull, b512, 0, stream>>>(x, Wk, nullptr, bk, kb, EMB, EMB, 1, 0, 1, 0);
        gemm128<<<gFull, b512, 0, stream>>>(x, Wv, nullptr, bv, VT, EMB, EMB, 1, 0, 1, 2);
        gemm128<<<gFull, b512, 0, stream>>>(x, Wq, nullptr, bq, qb, EMB, EMB, 1, 0, 1, 0);
        scale_q<<<dim3(BS * SLAB / (256 * 8)), b256, 0, stream>>>(qb);

        attn_kernel<<<gAtt, b512, 0, stream>>>(qb, qb + SLAB, kb, VT, pm);

        gemm128<<<gFull, b512, 0, stream>>>(qb, Wo, nullptr, bo, out, EMB, EMB, 0, 0, 0, 1);
    } else {
        bf16* qb0 = (bf16*)d_in[4];
        bf16* qb1 = (bf16*)d_in[6];
        u64*  pm  = (u64*)d_in[2];

        gemm128<<<gFull, b512, 0, stream>>>(x, Wk, nullptr, bk, kb, EMB, EMB, 1, 0, 1, 0);
        gemm128<<<gFull, b512, 0, stream>>>(x, Wv, nullptr, bv, VT, EMB, EMB, 1, 0, 1, 2);
        gemm128<<<gHalf, b512, 0, stream>>>(x, Wq, nullptr, bq, qb0, EMB, EMB, 1, 0,     1, 0);
        gemm128<<<gHalf, b512, 0, stream>>>(x, Wq, nullptr, bq, qb1, EMB, EMB, 1, S_LEN, 1, 0);
        scale_q<<<dim3(SLAB / (256 * 8)), b256, 0, stream>>>(qb0);
        scale_q<<<dim3(SLAB / (256 * 8)), b256, 0, stream>>>(qb1);
        pack_mask<<<gPk, b256, 0, stream>>>(mask, pm);

        attn_kernel<<<gAtt, b512, 0, stream>>>(qb0, qb1, kb, VT, pm);

        gemm128<<<gHalf, b512, 0, stream>>>(qb0, Wo, nullptr, bo, out,        EMB, EMB, 0, 0, 0, 1);
        gemm128<<<gHalf, b512, 0, stream>>>(qb1, Wo, nullptr, bo, out + SLAB, EMB, EMB, 0, 0, 0, 1);
    }
}

// Round 7
// 235.706 us; speedup vs baseline: 1.0410x; 1.0410x over previous
//
#include <hip/hip_runtime.h>

#define S_LEN 2048
#define EMB   1024
#define NH    16
#define HD    64
#define BS    2
#define QSCALE 0.18033688f   // 0.125 * log2(e): folded into Q so attn uses exp2 directly

typedef __bf16 bf16;
typedef bf16  bf16x8 __attribute__((ext_vector_type(8)));
typedef bf16  bf16x4 __attribute__((ext_vector_type(4)));
typedef float f32x4  __attribute__((ext_vector_type(4)));
typedef unsigned long long u64;
typedef unsigned int u32;

__device__ __forceinline__ bf16x8 ld8(const bf16* p){ return *(const bf16x8*)p; }

// async global->LDS, 16B/lane; LDS dest = wave-uniform base + lane*16
__device__ __forceinline__ void gl_lds16(const bf16* g, void* l) {
    __builtin_amdgcn_global_load_lds(
        (const __attribute__((address_space(1))) void*)g,
        (__attribute__((address_space(3))) void*)l,
        16, 0, 0);
}

// XOR swizzle: 16B groups within a 128B row
#define SW(row, g) ((((g) ^ ((row) & 7))) * 8)

// ---------------------------------------------------------------------------
// mask int32 [B*S, S] -> bits [B*S, S/64] u64.  (also used by fallbacks)
// ---------------------------------------------------------------------------
__global__ __launch_bounds__(256)
void pack_mask(const int* __restrict__ mask, u64* __restrict__ pm)
{
    int lane = threadIdx.x & 63;
    int row  = blockIdx.x * 4 + (threadIdx.x >> 6);
    const int* mr = mask + (size_t)row * S_LEN;
    u64* pr = pm + (size_t)row * (S_LEN / 64);
    for (int i = 0; i < S_LEN / 64; ++i) {
        u64 bits = __ballot(mr[i * 64 + lane] != 0);
        if (lane == 0) pr[i] = bits;
    }
}

// ---------------------------------------------------------------------------
// Fused prep: one launch replaces cvt_f32_bf16 (blocks 0..1023),
// pack_mask (1024..2047), transpose_w (2048..3071). Whole blocks take one
// path -> no divergence. Cuts per-iteration launch count 6 -> 4.
// ---------------------------------------------------------------------------
__global__ __launch_bounds__(256)
void prep(const float* __restrict__ x, bf16* __restrict__ xbf,
          const int* __restrict__ mask, u64* __restrict__ pm,
          const float* __restrict__ W0, const float* __restrict__ W1,
          const float* __restrict__ W2, const float* __restrict__ W3,
          bf16* __restrict__ Wt)
{
    const int bid = blockIdx.x;
    const int tid = threadIdx.x;
    __shared__ float T[64][68];

    if (bid < 1024) {                       // ---- x fp32 -> bf16
        size_t i = ((size_t)bid * 256 + tid) * 16;
        bf16 t[16];
        #pragma unroll
        for (int g = 0; g < 4; ++g) {
            f32x4 v = *(const f32x4*)(x + i + g * 4);
            #pragma unroll
            for (int j = 0; j < 4; ++j) t[g * 4 + j] = (bf16)v[j];
        }
        *(bf16x8*)(xbf + i)     = *(bf16x8*)t;
        *(bf16x8*)(xbf + i + 8) = *(bf16x8*)(t + 8);
    } else if (bid < 2048) {                // ---- mask -> bit-pack
        int lane = tid & 63;
        int row  = (bid - 1024) * 4 + (tid >> 6);
        const int* mr = mask + (size_t)row * S_LEN;
        u64* pr = pm + (size_t)row * (S_LEN / 64);
        for (int i = 0; i < S_LEN / 64; ++i) {
            u64 bits = __ballot(mr[i * 64 + lane] != 0);
            if (lane == 0) pr[i] = bits;
        }
    } else {                                // ---- weights -> bf16 W^T
        const int t   = bid - 2048;
        const int z   = t >> 8;
        const int rem = t & 255;
        const int k0 = (rem & 15) * 64, n0 = (rem >> 4) * 64;
        const float* W = z == 0 ? W0 : z == 1 ? W1 : z == 2 ? W2 : W3;
        const bool head = z < 3;
        {
            int k = k0 + (tid >> 2), cg = (tid & 3) * 16;
            size_t base = head ? ((size_t)(n0 >> 6) * ((size_t)EMB * HD) + (size_t)k * HD + cg)
                               : ((size_t)k * EMB + n0 + cg);
            #pragma unroll
            for (int g = 0; g < 4; ++g) {
                f32x4 v = *(const f32x4*)(W + base + g * 4);
                #pragma unroll
                for (int j = 0; j < 4; ++j) T[tid >> 2][cg + g * 4 + j] = v[j];
            }
        }
        __syncthreads();
        {
            int n = n0 + (tid >> 2), ck = (tid & 3) * 16;
            bf16 t16[16];
            #pragma unroll
            for (int j = 0; j < 16; ++j) t16[j] = (bf16)T[ck + j][tid >> 2];
            bf16* outp = Wt + (size_t)z * EMB * EMB + (size_t)n * EMB + k0 + ck;
            *(bf16x8*)outp       = *(bf16x8*)t16;
            *(bf16x8*)(outp + 8) = *(bf16x8*)(t16 + 8);
        }
    }
}

// ---------------------------------------------------------------------------
// scale Q in-place by QSCALE (fallback paths)
// ---------------------------------------------------------------------------
__global__ __launch_bounds__(256)
void scale_q(bf16* __restrict__ q)
{
    size_t i = ((size_t)blockIdx.x * 256 + threadIdx.x) * 8;
    bf16x8 v = *(bf16x8*)(q + i);
    #pragma unroll
    for (int j = 0; j < 8; ++j) v[j] = (bf16)((float)v[j] * QSCALE);
    *(bf16x8*)(q + i) = v;
}

// ---------------------------------------------------------------------------
// Fused QKV GEMM, m97 structure: 256 thr, tile 128x128, BK=64, 2x2 waves,
// 4x4 acc, global_load_lds staging. Epilogue routes z = n0>>10.
// R6 epilogue rework (store-issue was ~12.6M scalar b16 stores ~ 20us/CU
// floor, > the GEMM's own MFMA floor):
//   z=0/1 (Q,K): per-wave LDS transpose staging (Ush, wave-local lgkmcnt
//                sync only) -> 8 coalesced b128 stores/thread (was 64 b16).
//   z=2  (V^T): the 4 r-values are consecutive in t -> bf16x4 b64 stores.
// ---------------------------------------------------------------------------
__global__ __launch_bounds__(256, 3)
void gemm_qkv(const void* __restrict__ Ap, const bf16* __restrict__ Wt,
              const float* __restrict__ bqp, const float* __restrict__ bkp,
              const float* __restrict__ bvp,
              bf16* __restrict__ qb, bf16* __restrict__ kb, bf16* __restrict__ VT,
              int a32)
{
    const int tid  = threadIdx.x;
    const int lane = tid & 63, quad = lane >> 4, c = lane & 15;
    const int w = tid >> 6, wm = w >> 1, wn = w & 1;
    const int m0 = blockIdx.x * 128;
    const int n0 = blockIdx.y * 128;          // [0, 3072)

    __shared__ bf16 Ash[128][64];
    __shared__ bf16 Wsh[128][64];
    __shared__ bf16 Ush[4][16][72];           // epilogue transpose staging

    f32x4 acc[4][4];
    #pragma unroll
    for (int mt = 0; mt < 4; ++mt)
        #pragma unroll
        for (int nt = 0; nt < 4; ++nt) acc[mt][nt] = (f32x4){0.f,0.f,0.f,0.f};

    const int lrow = lane >> 3, lcol = (lane & 7) * 8;

    for (int k0 = 0; k0 < EMB; k0 += 64) {
        __syncthreads();
        if (!a32) {
            const bf16* A = (const bf16*)Ap;
            #pragma unroll
            for (int j = 0; j < 4; ++j)
                gl_lds16(A + (size_t)(m0 + w * 32 + j * 8 + lrow) * EMB + k0 + lcol,
                         &Ash[w * 32 + j * 8][0]);
        } else {
            const float* A = (const float*)Ap + (size_t)(m0 + (tid >> 1)) * EMB + k0 + (tid & 1) * 32;
            bf16 t[32];
            #pragma unroll
            for (int g = 0; g < 8; ++g) {
                f32x4 v = *(const f32x4*)(A + g * 4);
                #pragma unroll
                for (int j = 0; j < 4; ++j) t[g * 4 + j] = (bf16)v[j];
            }
            #pragma unroll
            for (int g2 = 0; g2 < 4; ++g2)
                *(bf16x8*)&Ash[tid >> 1][(tid & 1) * 32 + g2 * 8] = *(bf16x8*)(t + g2 * 8);
        }
        #pragma unroll
        for (int j = 0; j < 4; ++j)
            gl_lds16(Wt + (size_t)(n0 + w * 32 + j * 8 + lrow) * EMB + k0 + lcol,
                     &Wsh[w * 32 + j * 8][0]);
        __syncthreads();

        #pragma unroll
        for (int kh = 0; kh < 2; ++kh) {
            bf16x8 af[4], bfv[4];
            #pragma unroll
            for (int mt = 0; mt < 4; ++mt) af[mt]  = ld8(&Ash[wm * 64 + mt * 16 + c][kh * 32 + quad * 8]);
            #pragma unroll
            for (int nt = 0; nt < 4; ++nt) bfv[nt] = ld8(&Wsh[wn * 64 + nt * 16 + c][kh * 32 + quad * 8]);
            #pragma unroll
            for (int mt = 0; mt < 4; ++mt)
                #pragma unroll
                for (int nt = 0; nt < 4; ++nt)
                    acc[mt][nt] = __builtin_amdgcn_mfma_f32_16x16x32_bf16(af[mt], bfv[nt], acc[mt][nt], 0, 0, 0);
        }
    }

    const int z = n0 >> 10;   // block-uniform
    const float* bias = z == 0 ? bqp : z == 1 ? bkp : bvp;
    if (z == 2) {
        // V^T: vector b64 stores (r-values consecutive in t)
        #pragma unroll
        for (int nt = 0; nt < 4; ++nt) {
            int nn = (n0 & 1023) + wn * 64 + nt * 16 + c;
            float bv_ = bias[nn];
            int head = nn >> 6, d = nn & 63;
            #pragma unroll
            for (int mt = 0; mt < 4; ++mt) {
                int m = m0 + wm * 64 + mt * 16 + quad * 4;
                bf16x4 pv;
                #pragma unroll
                for (int r = 0; r < 4; ++r) pv[r] = (bf16)(acc[mt][nt][r] + bv_);
                *(bf16x4*)&VT[((size_t)((m >> 11) * NH + head) * HD + d) * S_LEN + (m & 2047)] = pv;
            }
        }
    } else {
        bf16* outb = z == 0 ? qb : kb;
        const float scl = z == 0 ? QSCALE : 1.0f;
        float bv4[4];
        #pragma unroll
        for (int nt = 0; nt < 4; ++nt) bv4[nt] = bias[(n0 & 1023) + wn * 64 + nt * 16 + c];
        #pragma unroll
        for (int mt = 0; mt < 4; ++mt) {
            // stage this wave's 16x64 row-slab, transposed into row-major
            #pragma unroll
            for (int nt = 0; nt < 4; ++nt)
                #pragma unroll
                for (int r = 0; r < 4; ++r)
                    Ush[w][quad * 4 + r][nt * 16 + c] = (bf16)((acc[mt][nt][r] + bv4[nt]) * scl);
            __builtin_amdgcn_s_waitcnt(0xc07f);    // lgkmcnt(0), wave-local
            int row16 = lane >> 2, cg = (lane & 3) * 16;
            int m = m0 + wm * 64 + mt * 16 + row16;
            int nn0 = (n0 & 1023) + wn * 64 + cg;
            bf16x8 v0 = *(bf16x8*)&Ush[w][row16][cg];
            bf16x8 v1 = *(bf16x8*)&Ush[w][row16][cg + 8];
            *(bf16x8*)&outb[(size_t)m * EMB + nn0]     = v0;
            *(bf16x8*)&outb[(size_t)m * EMB + nn0 + 8] = v1;
            __builtin_amdgcn_s_waitcnt(0xc07f);    // reads done before next mt
        }
    }
}

// ---------------------------------------------------------------------------
// Out-projection: 128x128 tile (clone of verified gemm_qkv structure,
// a32=0 path, fp32 epilogue). Grid (32, 8).
// ---------------------------------------------------------------------------
__global__ __launch_bounds__(256, 3)
void gemm_o(const bf16* __restrict__ Ap, const bf16* __restrict__ Wt,
            const float* __restrict__ bo, float* __restrict__ C)
{
    const int tid  = threadIdx.x;
    const int lane = tid & 63, quad = lane >> 4, c = lane & 15;
    const int w = tid >> 6, wm = w >> 1, wn = w & 1;
    const int m0 = blockIdx.x * 128;
    const int n0 = blockIdx.y * 128;

    __shared__ bf16 Ash[128][64];
    __shared__ bf16 Wsh[128][64];

    f32x4 acc[4][4];
    #pragma unroll
    for (int mt = 0; mt < 4; ++mt)
        #pragma unroll
        for (int nt = 0; nt < 4; ++nt) acc[mt][nt] = (f32x4){0.f,0.f,0.f,0.f};

    const int lrow = lane >> 3, lcol = (lane & 7) * 8;

    for (int k0 = 0; k0 < EMB; k0 += 64) {
        __syncthreads();
        #pragma unroll
        for (int j = 0; j < 4; ++j)
            gl_lds16(Ap + (size_t)(m0 + w * 32 + j * 8 + lrow) * EMB + k0 + lcol,
                     &Ash[w * 32 + j * 8][0]);
        #pragma unroll
        for (int j = 0; j < 4; ++j)
            gl_lds16(Wt + (size_t)(n0 + w * 32 + j * 8 + lrow) * EMB + k0 + lcol,
                     &Wsh[w * 32 + j * 8][0]);
        __syncthreads();

        #pragma unroll
        for (int kh = 0; kh < 2; ++kh) {
            bf16x8 af[4], bfv[4];
            #pragma unroll
            for (int mt = 0; mt < 4; ++mt) af[mt]  = ld8(&Ash[wm * 64 + mt * 16 + c][kh * 32 + quad * 8]);
            #pragma unroll
            for (int nt = 0; nt < 4; ++nt) bfv[nt] = ld8(&Wsh[wn * 64 + nt * 16 + c][kh * 32 + quad * 8]);
            #pragma unroll
            for (int mt = 0; mt < 4; ++mt)
                #pragma unroll
                for (int nt = 0; nt < 4; ++nt)
                    acc[mt][nt] = __builtin_amdgcn_mfma_f32_16x16x32_bf16(af[mt], bfv[nt], acc[mt][nt], 0, 0, 0);
        }
    }

    #pragma unroll
    for (int nt = 0; nt < 4; ++nt) {
        int n = n0 + wn * 64 + nt * 16 + c;
        float bv_ = bo[n];
        #pragma unroll
        for (int mt = 0; mt < 4; ++mt)
            #pragma unroll
            for (int r = 0; r < 4; ++r) {
                int m = m0 + wm * 64 + mt * 16 + quad * 4 + r;
                C[(size_t)m * EMB + n] = acc[mt][nt][r] + bv_;
            }
    }
}

// ---------------------------------------------------------------------------
// Fallback GEMM (R7, verified): 128x128 tile, 512 thr, register staging.
// ---------------------------------------------------------------------------
__global__ __launch_bounds__(512)
void gemm128(const void* __restrict__ Ap, const float* __restrict__ Wp,
             const bf16* __restrict__ Wtp, const float* __restrict__ bias,
             void* __restrict__ Cp, int N, int K, int whead,
             int m_base, int a32, int cmode)
{
    const int tid  = threadIdx.x;
    const int lane = tid & 63, quad = lane >> 4, c = lane & 15;
    const int w = tid >> 6, wm = w >> 2, wn = w & 3;
    const int m0 = blockIdx.x * 128, n0 = blockIdx.y * 128;

    __shared__ bf16 Ash[128][64];
    __shared__ bf16 Wsh[128][64];

    f32x4 acc[4][2];
    #pragma unroll
    for (int mt = 0; mt < 4; ++mt)
        #pragma unroll
        for (int nt = 0; nt < 2; ++nt) acc[mt][nt] = (f32x4){0.f,0.f,0.f,0.f};

    const int arow = tid >> 2, aq = tid & 3;

    auto compute = [&]() {
        #pragma unroll
        for (int kh = 0; kh < 2; ++kh) {
            bf16x8 bfr[2];
            #pragma unroll
            for (int nt = 0; nt < 2; ++nt) {
                int rw = wn * 32 + nt * 16 + c;
                bfr[nt] = ld8(&Wsh[rw][SW(rw, kh * 4 + quad)]);
            }
            #pragma unroll
            for (int mt = 0; mt < 4; ++mt) {
                int ra = wm * 64 + mt * 16 + c;
                bf16x8 af = ld8(&Ash[ra][SW(ra, kh * 4 + quad)]);
                #pragma unroll
                for (int nt = 0; nt < 2; ++nt)
                    acc[mt][nt] = __builtin_amdgcn_mfma_f32_16x16x32_bf16(af, bfr[nt], acc[mt][nt], 0, 0, 0);
            }
        }
    };

    for (int k0 = 0; k0 < K; k0 += 64) {
        __syncthreads();
        if (a32) {
            const float* A = (const float*)Ap + (size_t)(m_base + m0 + arow) * K + k0 + aq * 16;
            bf16 t16[16];
            #pragma unroll
            for (int g = 0; g < 4; ++g) {
                f32x4 v = *(const f32x4*)(A + g * 4);
                #pragma unroll
                for (int j = 0; j < 4; ++j) t16[g * 4 + j] = (bf16)v[j];
            }
            *(bf16x8*)&Ash[arow][SW(arow, aq * 2)]     = *(bf16x8*)t16;
            *(bf16x8*)&Ash[arow][SW(arow, aq * 2 + 1)] = *(bf16x8*)(t16 + 8);
        } else {
            const bf16* A = (const bf16*)Ap + (size_t)(m_base + m0 + arow) * K + k0 + aq * 16;
            *(bf16x8*)&Ash[arow][SW(arow, aq * 2)]     = ld8(A);
            *(bf16x8*)&Ash[arow][SW(arow, aq * 2 + 1)] = ld8(A + 8);
        }
        {
            int nl = tid & 127, kg = tid >> 7;
            int n = n0 + nl;
            size_t base    = whead ? ((size_t)(n >> 6) * ((size_t)K * HD) + (n & 63))
                                   : (size_t)n;
            size_t kstride = whead ? (size_t)HD : (size_t)N;
            #pragma unroll
            for (int p = 0; p < 2; ++p) {
                int grp = kg + 4 * p;
                bf16 t8[8];
                #pragma unroll
                for (int j = 0; j < 8; ++j)
                    t8[j] = (bf16)Wp[base + (size_t)(k0 + grp * 8 + j) * kstride];
                *(bf16x8*)&Wsh[nl][SW(nl, grp)] = *(bf16x8*)t8;
            }
        }
        __syncthreads();
        compute();
    }

    #pragma unroll
    for (int nt = 0; nt < 2; ++nt) {
        int n = n0 + wn * 32 + nt * 16 + c;
        float bv_ = bias[n];
        #pragma unroll
        for (int mt = 0; mt < 4; ++mt)
            #pragma unroll
            for (int r = 0; r < 4; ++r) {
                int m = m0 + wm * 64 + mt * 16 + quad * 4 + r;
                float v = acc[mt][nt][r] + bv_;
                if (cmode == 0)      ((bf16*)Cp)[(size_t)m * N + n] = (bf16)v;
                else if (cmode == 1) ((float*)Cp)[(size_t)m * N + n] = v;
                else {
                    int mm = m_base + m;
                    ((bf16*)Cp)[((size_t)((mm >> 11) * NH + (n >> 6)) * HD + (n & 63)) * S_LEN + (mm & 2047)] = (bf16)v;
                }
            }
    }
}

// ---------------------------------------------------------------------------
// Flash attention, S^T orientation. 512 thr = 8 waves x 16 q-rows, q-tile 128.
// R4-exact (best measured: 60.4us): baseline inner loop (Psh round-trip,
// VALU l-accum, shuffle epilogue, no setprio) + XCD-chunked block remap
// (FETCH 70->14.4MB). R1/R2/R3/R5 variants all refuted -- kernel is
// latency-bound at the grid-capped 2 blocks/CU; inner-loop reshuffles and
// LDS-traffic cuts are neutral or negative. FROZEN.
// ---------------------------------------------------------------------------
__global__ __launch_bounds__(512, 2)
void attn_kernel(bf16* q0p, bf16* q1p, const bf16* __restrict__ kbuf,
                 const bf16* __restrict__ VTg, const u64* __restrict__ pmask)
{
    const int tid  = threadIdx.x;
    const int w    = tid >> 6;          // 0..7
    const int lane = tid & 63;
    const int quad = lane >> 4;
    const int c    = lane & 15;
    // XCD-chunked bijective remap (gridDim = 16 x 32 = 512 blocks)
    const int flat  = blockIdx.y * 16 + blockIdx.x;
    const int flat2 = (flat & 7) * 64 + (flat >> 3);
    const int q0   = (flat2 & 15) * 128;
    const int bh   = flat2 >> 4;
    const int b    = bh >> 4, h = bh & 15;

    bf16* qc = b ? q1p : q0p;
    const bf16* kh_ = kbuf + (size_t)b * S_LEN * EMB + h * HD;
    const bf16* vt  = VTg + (size_t)bh * HD * S_LEN;

    __shared__ bf16 Ksh [2][64][64];
    __shared__ bf16 VTsh[2][64][64];
    __shared__ bf16 Psh[8][16][64];

    // Q fragments (B-operand): wave owns rows q0 + w*16 + c
    bf16x8 qf[2];
    #pragma unroll
    for (int kk = 0; kk < 2; ++kk)
        qf[kk] = ld8(qc + (size_t)(q0 + w * 16 + c) * EMB + h * HD + kk * 32 + quad * 8);

    const u64* pmr = pmask + (size_t)(b * S_LEN + q0 + w * 16 + c) * (S_LEN / 64);

    f32x4 l4 = (f32x4){0.f,0.f,0.f,0.f};
    f32x4 o[4];
    #pragma unroll
    for (int dt = 0; dt < 4; ++dt) o[dt] = (f32x4){0.f,0.f,0.f,0.f};

    const int srow = tid >> 3, sg = tid & 7;   // 64 rows x 8 groups
    bf16x8 kr, vr;
    auto loadKV = [&](int t0) {
        kr = ld8(kh_ + (size_t)(t0 + srow) * EMB + sg * 8);
        vr = ld8(vt + (size_t)srow * S_LEN + t0 + sg * 8);
    };

    loadKV(0);
    int buf = 0;
    for (int t0 = 0; t0 < S_LEN; t0 += 64) {
        *(bf16x8*)&Ksh [buf][srow][SW(srow, sg)] = kr;
        *(bf16x8*)&VTsh[buf][srow][SW(srow, sg)] = vr;
        __syncthreads();                       // single barrier per chunk (dbuf)
        if (t0 + 64 < S_LEN) loadKV(t0 + 64);

        u64 s0 = pmr[t0 >> 6] >> (quad * 4);
        u32 mm[2] = {(u32)s0, (u32)(s0 >> 32)};

        // S^T = K . Q^T
        f32x4 sc[4];
        #pragma unroll
        for (int tt = 0; tt < 4; ++tt) sc[tt] = (f32x4){0.f,0.f,0.f,0.f};
        #pragma unroll
        for (int tt = 0; tt < 4; ++tt)
            #pragma unroll
            for (int kk = 0; kk < 2; ++kk) {
                int rk = tt * 16 + c;
                bf16x8 ka = ld8(&Ksh[buf][rk][SW(rk, kk * 4 + quad)]);
                sc[tt] = __builtin_amdgcn_mfma_f32_16x16x32_bf16(ka, qf[kk], sc[tt], 0, 0, 0);
            }

        // per-lane softmax: p = mask ? exp2(s) : 0
        #pragma unroll
        for (int tt = 0; tt < 4; ++tt) {
            u32 half = mm[tt >> 1];
            bf16x4 pv;
            #pragma unroll
            for (int r = 0; r < 4; ++r) {
                float e = __builtin_amdgcn_exp2f(sc[tt][r]);
                e = ((half >> ((tt & 1) * 16 + r)) & 1) ? e : 0.f;
                l4[r] += e;
                pv[r] = (bf16)e;
            }
            *(bf16x4*)&Psh[w][c][SW(c, tt * 2 + (quad >> 1)) + (quad & 1) * 4] = pv;
        }
        __builtin_amdgcn_s_waitcnt(0xc07f);    // lgkmcnt(0) only (same-wave P)

        // O^T += V^T . P^T
        #pragma unroll
        for (int th = 0; th < 2; ++th) {
            bf16x8 pf = ld8(&Psh[w][c][SW(c, th * 4 + quad)]);
            #pragma unroll
            for (int dt = 0; dt < 4; ++dt) {
                int rv = dt * 16 + c;
                bf16x8 av = ld8(&VTsh[buf][rv][SW(rv, th * 4 + quad)]);
                o[dt] = __builtin_amdgcn_mfma_f32_16x16x32_bf16(av, pf, o[dt], 0, 0, 0);
            }
        }
        buf ^= 1;
    }

    // epilogue: reduce l across quads (lanes sharing s=c), normalize, write
    float ls = l4[0] + l4[1] + l4[2] + l4[3];
    ls += __shfl_xor(ls, 16);
    ls += __shfl_xor(ls, 32);
    float inv = 1.0f / fmaxf(ls, 1e-30f);
    #pragma unroll
    for (int dt = 0; dt < 4; ++dt) {
        bf16x4 ov;
        #pragma unroll
        for (int r = 0; r < 4; ++r) ov[r] = (bf16)(o[dt][r] * inv);
        *(bf16x4*)&qc[(size_t)(q0 + w * 16 + c) * EMB + h * HD + dt * 16 + quad * 4] = ov;
    }
}

// ---------------------------------------------------------------------------
// d_out: V^T [0:8MB) + K [8:16MB) (consumed by attn before fp32 out-proj).
// ---------------------------------------------------------------------------
extern "C" void kernel_launch(void* const* d_in, const int* in_sizes, int n_in,
                              void* d_out, int out_size, void* d_ws, size_t ws_size,
                              hipStream_t stream)
{
    const float* x    = (const float*)d_in[0];
    const int*   mask = (const int*)d_in[1];
    const float* Wq   = (const float*)d_in[2];
    const float* bq   = (const float*)d_in[3];
    const float* Wk   = (const float*)d_in[4];
    const float* bk   = (const float*)d_in[5];
    const float* Wv   = (const float*)d_in[6];
    const float* bv   = (const float*)d_in[7];
    const float* Wo   = (const float*)d_in[8];
    const float* bo   = (const float*)d_in[9];
    float* out = (float*)d_out;

    const size_t SLAB = (size_t)S_LEN * EMB;
    const size_t QB = (size_t)BS * SLAB * sizeof(bf16);          // 8 MB
    const size_t WT = (size_t)4 * EMB * EMB * sizeof(bf16);      // 8 MB
    const size_t PM = (size_t)BS * S_LEN * (S_LEN / 64) * 8;     // 1 MB
    const size_t XB = (size_t)BS * SLAB * sizeof(bf16);          // 8 MB

    bf16* VT = (bf16*)d_out;
    bf16* kb = (bf16*)d_out + BS * SLAB;

    dim3 b256(256), b512(512);
    dim3 gAtt (S_LEN / 128, BS * NH);
    dim3 gPk  (BS * S_LEN / 4);
    dim3 gFull(BS * S_LEN / 128, EMB / 128);
    dim3 gHalf(S_LEN / 128, EMB / 128);

    if (ws_size >= QB + WT + PM + XB + 64) {
        bf16* qb  = (bf16*)d_ws;
        bf16* Wt  = (bf16*)((char*)d_ws + QB);
        u64*  pm  = (u64*)((char*)d_ws + QB + WT);
        bf16* xbf = (bf16*)((char*)d_ws + QB + WT + PM);

        prep<<<dim3(3072), b256, 0, stream>>>(x, xbf, mask, pm, Wq, Wk, Wv, Wo, Wt);

        gemm_qkv<<<dim3(BS * S_LEN / 128, 3 * EMB / 128), b256, 0, stream>>>(
            xbf, Wt, bq, bk, bv, qb, kb, VT, 0);

        attn_kernel<<<gAtt, b512, 0, stream>>>(qb, qb + SLAB, kb, VT, pm);

        gemm_o<<<dim3(BS * S_LEN / 128, EMB / 128), b256, 0, stream>>>(
            qb, Wt + (size_t)3 * EMB * EMB, bo, out);
    } else if (ws_size >= QB + PM + 64) {
        bf16* qb = (bf16*)d_ws;
        u64*  pm = (u64*)((char*)d_ws + QB);
        pack_mask<<<gPk, b256, 0, stream>>>(mask, pm);

        gemm128<<<gFull, b512, 0, stream>>>(x, Wk, nullptr, bk, kb, EMB, EMB, 1, 0, 1, 0);
        gemm128<<<gFull, b512, 0, stream>>>(x, Wv, nullptr, bv, VT, EMB, EMB, 1, 0, 1, 2);
        gemm128<<<gFull, b512, 0, stream>>>(x, Wq, nullptr, bq, qb, EMB, EMB, 1, 0, 1, 0);
        scale_q<<<dim3(BS * SLAB / (256 * 8)), b256, 0, stream>>>(qb);

        attn_kernel<<<gAtt, b512, 0, stream>>>(qb, qb + SLAB, kb, VT, pm);

        gemm128<<<gFull, b512, 0, stream>>>(qb, Wo, nullptr, bo, out, EMB, EMB, 0, 0, 0, 1);
    } else {
        bf16* qb0 = (bf16*)d_in[4];
        bf16* qb1 = (bf16*)d_in[6];
        u64*  pm  = (u64*)d_in[2];

        gemm128<<<gFull, b512, 0, stream>>>(x, Wk, nullptr, bk, kb, EMB, EMB, 1, 0, 1, 0);
        gemm128<<<gFull, b512, 0, stream>>>(x, Wv, nullptr, bv, VT, EMB, EMB, 1, 0, 1, 2);
        gemm128<<<gHalf, b512, 0, stream>>>(x, Wq, nullptr, bq, qb0, EMB, EMB, 1, 0,     1, 0);
        gemm128<<<gHalf, b512, 0, stream>>>(x, Wq, nullptr, bq, qb1, EMB, EMB, 1, S_LEN, 1, 0);
        scale_q<<<dim3(SLAB / (256 * 8)), b256, 0, stream>>>(qb0);
        scale_q<<<dim3(SLAB / (256 * 8)), b256, 0, stream>>>(qb1);
        pack_mask<<<gPk, b256, 0, stream>>>(mask, pm);

        attn_kernel<<<gAtt, b512, 0, stream>>>(qb0, qb1, kb, VT, pm);

        gemm128<<<gHalf, b512, 0, stream>>>(qb0, Wo, nullptr, bo, out,        EMB, EMB, 0, 0, 0, 1);
        gemm128<<<gHalf, b512, 0, stream>>>(qb1, Wo, nullptr, bo, out + SLAB, EMB, EMB, 0, 0, 0, 1);
    }
}

// Round 8
// 230.781 us; speedup vs baseline: 1.0632x; 1.0213x over previous
//
#include <hip/hip_runtime.h>

#define S_LEN 2048
#define EMB   1024
#define NH    16
#define HD    64
#define BS    2
#define QSCALE 0.18033688f   // 0.125 * log2(e): folded into Q so attn uses exp2 directly

typedef __bf16 bf16;
typedef bf16  bf16x8 __attribute__((ext_vector_type(8)));
typedef bf16  bf16x4 __attribute__((ext_vector_type(4)));
typedef float f32x4  __attribute__((ext_vector_type(4)));
typedef unsigned long long u64;
typedef unsigned int u32;

__device__ __forceinline__ bf16x8 ld8(const bf16* p){ return *(const bf16x8*)p; }

// async global->LDS, 16B/lane; LDS dest = wave-uniform base + lane*16
__device__ __forceinline__ void gl_lds16(const bf16* g, void* l) {
    __builtin_amdgcn_global_load_lds(
        (const __attribute__((address_space(1))) void*)g,
        (__attribute__((address_space(3))) void*)l,
        16, 0, 0);
}

// XOR swizzle: 16B groups within a 128B row
#define SW(row, g) ((((g) ^ ((row) & 7))) * 8)

// ---------------------------------------------------------------------------
// mask int32 [B*S, S] -> bits [B*S, S/64] u64.  (also used by fallbacks)
// ---------------------------------------------------------------------------
__global__ __launch_bounds__(256)
void pack_mask(const int* __restrict__ mask, u64* __restrict__ pm)
{
    int lane = threadIdx.x & 63;
    int row  = blockIdx.x * 4 + (threadIdx.x >> 6);
    const int* mr = mask + (size_t)row * S_LEN;
    u64* pr = pm + (size_t)row * (S_LEN / 64);
    for (int i = 0; i < S_LEN / 64; ++i) {
        u64 bits = __ballot(mr[i * 64 + lane] != 0);
        if (lane == 0) pr[i] = bits;
    }
}

// ---------------------------------------------------------------------------
// Fused prep: one launch replaces cvt_f32_bf16 (blocks 0..1023),
// pack_mask (1024..2047), transpose_w (2048..3071).
// ---------------------------------------------------------------------------
__global__ __launch_bounds__(256)
void prep(const float* __restrict__ x, bf16* __restrict__ xbf,
          const int* __restrict__ mask, u64* __restrict__ pm,
          const float* __restrict__ W0, const float* __restrict__ W1,
          const float* __restrict__ W2, const float* __restrict__ W3,
          bf16* __restrict__ Wt)
{
    const int bid = blockIdx.x;
    const int tid = threadIdx.x;
    __shared__ float T[64][68];

    if (bid < 1024) {                       // ---- x fp32 -> bf16
        size_t i = ((size_t)bid * 256 + tid) * 16;
        bf16 t[16];
        #pragma unroll
        for (int g = 0; g < 4; ++g) {
            f32x4 v = *(const f32x4*)(x + i + g * 4);
            #pragma unroll
            for (int j = 0; j < 4; ++j) t[g * 4 + j] = (bf16)v[j];
        }
        *(bf16x8*)(xbf + i)     = *(bf16x8*)t;
        *(bf16x8*)(xbf + i + 8) = *(bf16x8*)(t + 8);
    } else if (bid < 2048) {                // ---- mask -> bit-pack
        int lane = tid & 63;
        int row  = (bid - 1024) * 4 + (tid >> 6);
        const int* mr = mask + (size_t)row * S_LEN;
        u64* pr = pm + (size_t)row * (S_LEN / 64);
        for (int i = 0; i < S_LEN / 64; ++i) {
            u64 bits = __ballot(mr[i * 64 + lane] != 0);
            if (lane == 0) pr[i] = bits;
        }
    } else {                                // ---- weights -> bf16 W^T
        const int t   = bid - 2048;
        const int z   = t >> 8;
        const int rem = t & 255;
        const int k0 = (rem & 15) * 64, n0 = (rem >> 4) * 64;
        const float* W = z == 0 ? W0 : z == 1 ? W1 : z == 2 ? W2 : W3;
        const bool head = z < 3;
        {
            int k = k0 + (tid >> 2), cg = (tid & 3) * 16;
            size_t base = head ? ((size_t)(n0 >> 6) * ((size_t)EMB * HD) + (size_t)k * HD + cg)
                               : ((size_t)k * EMB + n0 + cg);
            #pragma unroll
            for (int g = 0; g < 4; ++g) {
                f32x4 v = *(const f32x4*)(W + base + g * 4);
                #pragma unroll
                for (int j = 0; j < 4; ++j) T[tid >> 2][cg + g * 4 + j] = v[j];
            }
        }
        __syncthreads();
        {
            int n = n0 + (tid >> 2), ck = (tid & 3) * 16;
            bf16 t16[16];
            #pragma unroll
            for (int j = 0; j < 16; ++j) t16[j] = (bf16)T[ck + j][tid >> 2];
            bf16* outp = Wt + (size_t)z * EMB * EMB + (size_t)n * EMB + k0 + ck;
            *(bf16x8*)outp       = *(bf16x8*)t16;
            *(bf16x8*)(outp + 8) = *(bf16x8*)(t16 + 8);
        }
    }
}

// ---------------------------------------------------------------------------
// scale Q in-place by QSCALE (fallback paths)
// ---------------------------------------------------------------------------
__global__ __launch_bounds__(256)
void scale_q(bf16* __restrict__ q)
{
    size_t i = ((size_t)blockIdx.x * 256 + threadIdx.x) * 8;
    bf16x8 v = *(bf16x8*)(q + i);
    #pragma unroll
    for (int j = 0; j < 8; ++j) v[j] = (bf16)((float)v[j] * QSCALE);
    *(bf16x8*)(q + i) = v;
}

// ---------------------------------------------------------------------------
// Fused QKV GEMM, m97 structure: 256 thr, tile 128x128, BK=64, 2x2 waves,
// 4x4 acc, global_load_lds staging, R6 vectorized epilogues.
// R8: XCD-chunked block remap — grid (32,24)=768 blocks, 96/XCD arranged as
// 8 m-tiles x 12 n-tiles (L2 footprint 8*256K A + 12*256K B = 5 MB vs the
// default round-robin needing all 24 B-panels = 6 MB + full A re-fetch).
// ---------------------------------------------------------------------------
__global__ __launch_bounds__(256, 3)
void gemm_qkv(const void* __restrict__ Ap, const bf16* __restrict__ Wt,
              const float* __restrict__ bqp, const float* __restrict__ bkp,
              const float* __restrict__ bvp,
              bf16* __restrict__ qb, bf16* __restrict__ kb, bf16* __restrict__ VT,
              int a32)
{
    const int tid  = threadIdx.x;
    const int lane = tid & 63, quad = lane >> 4, c = lane & 15;
    const int w = tid >> 6, wm = w >> 1, wn = w & 1;
    // XCD-chunked bijective remap: xcd = flat%8 heuristic
    const int flat = blockIdx.y * 32 + blockIdx.x;
    const int xcd = flat & 7, li = flat >> 3;            // li 0..95
    const int m0 = ((xcd >> 1) * 8 + (li & 7)) * 128;    // 32 m-tiles
    const int n0 = ((xcd & 1) * 12 + (li >> 3)) * 128;   // 24 n-tiles

    __shared__ bf16 Ash[128][64];
    __shared__ bf16 Wsh[128][64];
    __shared__ bf16 Ush[4][16][72];           // epilogue transpose staging

    f32x4 acc[4][4];
    #pragma unroll
    for (int mt = 0; mt < 4; ++mt)
        #pragma unroll
        for (int nt = 0; nt < 4; ++nt) acc[mt][nt] = (f32x4){0.f,0.f,0.f,0.f};

    const int lrow = lane >> 3, lcol = (lane & 7) * 8;

    for (int k0 = 0; k0 < EMB; k0 += 64) {
        __syncthreads();
        if (!a32) {
            const bf16* A = (const bf16*)Ap;
            #pragma unroll
            for (int j = 0; j < 4; ++j)
                gl_lds16(A + (size_t)(m0 + w * 32 + j * 8 + lrow) * EMB + k0 + lcol,
                         &Ash[w * 32 + j * 8][0]);
        } else {
            const float* A = (const float*)Ap + (size_t)(m0 + (tid >> 1)) * EMB + k0 + (tid & 1) * 32;
            bf16 t[32];
            #pragma unroll
            for (int g = 0; g < 8; ++g) {
                f32x4 v = *(const f32x4*)(A + g * 4);
                #pragma unroll
                for (int j = 0; j < 4; ++j) t[g * 4 + j] = (bf16)v[j];
            }
            #pragma unroll
            for (int g2 = 0; g2 < 4; ++g2)
                *(bf16x8*)&Ash[tid >> 1][(tid & 1) * 32 + g2 * 8] = *(bf16x8*)(t + g2 * 8);
        }
        #pragma unroll
        for (int j = 0; j < 4; ++j)
            gl_lds16(Wt + (size_t)(n0 + w * 32 + j * 8 + lrow) * EMB + k0 + lcol,
                     &Wsh[w * 32 + j * 8][0]);
        __syncthreads();

        #pragma unroll
        for (int kh = 0; kh < 2; ++kh) {
            bf16x8 af[4], bfv[4];
            #pragma unroll
            for (int mt = 0; mt < 4; ++mt) af[mt]  = ld8(&Ash[wm * 64 + mt * 16 + c][kh * 32 + quad * 8]);
            #pragma unroll
            for (int nt = 0; nt < 4; ++nt) bfv[nt] = ld8(&Wsh[wn * 64 + nt * 16 + c][kh * 32 + quad * 8]);
            #pragma unroll
            for (int mt = 0; mt < 4; ++mt)
                #pragma unroll
                for (int nt = 0; nt < 4; ++nt)
                    acc[mt][nt] = __builtin_amdgcn_mfma_f32_16x16x32_bf16(af[mt], bfv[nt], acc[mt][nt], 0, 0, 0);
        }
    }

    const int z = n0 >> 10;   // block-uniform
    const float* bias = z == 0 ? bqp : z == 1 ? bkp : bvp;
    if (z == 2) {
        // V^T: vector b64 stores (r-values consecutive in t)
        #pragma unroll
        for (int nt = 0; nt < 4; ++nt) {
            int nn = (n0 & 1023) + wn * 64 + nt * 16 + c;
            float bv_ = bias[nn];
            int head = nn >> 6, d = nn & 63;
            #pragma unroll
            for (int mt = 0; mt < 4; ++mt) {
                int m = m0 + wm * 64 + mt * 16 + quad * 4;
                bf16x4 pv;
                #pragma unroll
                for (int r = 0; r < 4; ++r) pv[r] = (bf16)(acc[mt][nt][r] + bv_);
                *(bf16x4*)&VT[((size_t)((m >> 11) * NH + head) * HD + d) * S_LEN + (m & 2047)] = pv;
            }
        }
    } else {
        bf16* outb = z == 0 ? qb : kb;
        const float scl = z == 0 ? QSCALE : 1.0f;
        float bv4[4];
        #pragma unroll
        for (int nt = 0; nt < 4; ++nt) bv4[nt] = bias[(n0 & 1023) + wn * 64 + nt * 16 + c];
        #pragma unroll
        for (int mt = 0; mt < 4; ++mt) {
            // stage this wave's 16x64 row-slab, transposed into row-major
            #pragma unroll
            for (int nt = 0; nt < 4; ++nt)
                #pragma unroll
                for (int r = 0; r < 4; ++r)
                    Ush[w][quad * 4 + r][nt * 16 + c] = (bf16)((acc[mt][nt][r] + bv4[nt]) * scl);
            __builtin_amdgcn_s_waitcnt(0xc07f);    // lgkmcnt(0), wave-local
            int row16 = lane >> 2, cg = (lane & 3) * 16;
            int m = m0 + wm * 64 + mt * 16 + row16;
            int nn0 = (n0 & 1023) + wn * 64 + cg;
            bf16x8 v0 = *(bf16x8*)&Ush[w][row16][cg];
            bf16x8 v1 = *(bf16x8*)&Ush[w][row16][cg + 8];
            *(bf16x8*)&outb[(size_t)m * EMB + nn0]     = v0;
            *(bf16x8*)&outb[(size_t)m * EMB + nn0 + 8] = v1;
            __builtin_amdgcn_s_waitcnt(0xc07f);    // reads done before next mt
        }
    }
}

// ---------------------------------------------------------------------------
// Out-projection: BACK to 128x64 tile (R4's 128x128 = 256 blocks = 1 blk/CU
// exposed every barrier drain; cross-round delta ~ +5us). 512 blocks, 2/CU.
// R8: fp32 epilogue via LDS-transpose (aliased onto Ash, no LDS growth):
// 32 scalar dword stores/thread -> 8 dwordx4. + XCD-chunked remap (8m x 8n
// per XCD = 3 MB L2 footprint).
// ---------------------------------------------------------------------------
__global__ __launch_bounds__(256, 4)
void gemm_o(const bf16* __restrict__ Ap, const bf16* __restrict__ Wt,
            const float* __restrict__ bo, float* __restrict__ C)
{
    const int tid  = threadIdx.x;
    const int lane = tid & 63, quad = lane >> 4, c = lane & 15;
    const int w = tid >> 6, wm = w >> 1, wn = w & 1;
    // XCD-chunked remap: grid (32,16)=512, 64/XCD as 8m x 8n
    const int flat = blockIdx.y * 32 + blockIdx.x;
    const int xcd = flat & 7, li = flat >> 3;          // li 0..63
    const int m0 = ((xcd >> 1) * 8 + (li & 7)) * 128;  // 32 m-tiles
    const int n0 = ((xcd & 1) * 8 + (li >> 3)) * 64;   // 16 n-tiles

    __shared__ bf16 Ash[128][64];
    __shared__ bf16 Wsh[64][64];

    f32x4 acc[4][2];
    #pragma unroll
    for (int mt = 0; mt < 4; ++mt)
        #pragma unroll
        for (int nt = 0; nt < 2; ++nt) acc[mt][nt] = (f32x4){0.f,0.f,0.f,0.f};

    const int lrow = lane >> 3, lcol = (lane & 7) * 8;

    for (int k0 = 0; k0 < EMB; k0 += 64) {
        __syncthreads();
        #pragma unroll
        for (int j = 0; j < 4; ++j)
            gl_lds16(Ap + (size_t)(m0 + w * 32 + j * 8 + lrow) * EMB + k0 + lcol,
                     &Ash[w * 32 + j * 8][0]);
        #pragma unroll
        for (int j = 0; j < 2; ++j)
            gl_lds16(Wt + (size_t)(n0 + w * 16 + j * 8 + lrow) * EMB + k0 + lcol,
                     &Wsh[w * 16 + j * 8][0]);
        __syncthreads();

        #pragma unroll
        for (int kh = 0; kh < 2; ++kh) {
            bf16x8 af[4], bfv[2];
            #pragma unroll
            for (int mt = 0; mt < 4; ++mt) af[mt]  = ld8(&Ash[wm * 64 + mt * 16 + c][kh * 32 + quad * 8]);
            #pragma unroll
            for (int nt = 0; nt < 2; ++nt) bfv[nt] = ld8(&Wsh[wn * 32 + nt * 16 + c][kh * 32 + quad * 8]);
            #pragma unroll
            for (int mt = 0; mt < 4; ++mt)
                #pragma unroll
                for (int nt = 0; nt < 2; ++nt)
                    acc[mt][nt] = __builtin_amdgcn_mfma_f32_16x16x32_bf16(af[mt], bfv[nt], acc[mt][nt], 0, 0, 0);
        }
    }

    // epilogue: reuse Ash as f32 transpose staging (4 x 16 x 36 floats = 9216B)
    __syncthreads();                          // all Ash compute reads complete
    float (*Ush)[16][36] = (float(*)[16][36])&Ash[0][0];
    float bv2[2];
    #pragma unroll
    for (int nt = 0; nt < 2; ++nt) bv2[nt] = bo[n0 + wn * 32 + nt * 16 + c];
    #pragma unroll
    for (int mt = 0; mt < 4; ++mt) {
        #pragma unroll
        for (int nt = 0; nt < 2; ++nt)
            #pragma unroll
            for (int r = 0; r < 4; ++r)
                Ush[w][quad * 4 + r][nt * 16 + c] = acc[mt][nt][r] + bv2[nt];
        __builtin_amdgcn_s_waitcnt(0xc07f);   // lgkmcnt(0), wave-local
        int row16 = lane >> 2, cg = (lane & 3) * 8;
        int m = m0 + wm * 64 + mt * 16 + row16;
        int nn = n0 + wn * 32 + cg;
        f32x4 v0 = *(f32x4*)&Ush[w][row16][cg];
        f32x4 v1 = *(f32x4*)&Ush[w][row16][cg + 4];
        *(f32x4*)&C[(size_t)m * EMB + nn]     = v0;
        *(f32x4*)&C[(size_t)m * EMB + nn + 4] = v1;
        __builtin_amdgcn_s_waitcnt(0xc07f);   // reads done before next mt
    }
}

// ---------------------------------------------------------------------------
// Fallback GEMM (R7, verified): 128x128 tile, 512 thr, register staging.
// ---------------------------------------------------------------------------
__global__ __launch_bounds__(512)
void gemm128(const void* __restrict__ Ap, const float* __restrict__ Wp,
             const bf16* __restrict__ Wtp, const float* __restrict__ bias,
             void* __restrict__ Cp, int N, int K, int whead,
             int m_base, int a32, int cmode)
{
    const int tid  = threadIdx.x;
    const int lane = tid & 63, quad = lane >> 4, c = lane & 15;
    const int w = tid >> 6, wm = w >> 2, wn = w & 3;
    const int m0 = blockIdx.x * 128, n0 = blockIdx.y * 128;

    __shared__ bf16 Ash[128][64];
    __shared__ bf16 Wsh[128][64];

    f32x4 acc[4][2];
    #pragma unroll
    for (int mt = 0; mt < 4; ++mt)
        #pragma unroll
        for (int nt = 0; nt < 2; ++nt) acc[mt][nt] = (f32x4){0.f,0.f,0.f,0.f};

    const int arow = tid >> 2, aq = tid & 3;

    auto compute = [&]() {
        #pragma unroll
        for (int kh = 0; kh < 2; ++kh) {
            bf16x8 bfr[2];
            #pragma unroll
            for (int nt = 0; nt < 2; ++nt) {
                int rw = wn * 32 + nt * 16 + c;
                bfr[nt] = ld8(&Wsh[rw][SW(rw, kh * 4 + quad)]);
            }
            #pragma unroll
            for (int mt = 0; mt < 4; ++mt) {
                int ra = wm * 64 + mt * 16 + c;
                bf16x8 af = ld8(&Ash[ra][SW(ra, kh * 4 + quad)]);
                #pragma unroll
                for (int nt = 0; nt < 2; ++nt)
                    acc[mt][nt] = __builtin_amdgcn_mfma_f32_16x16x32_bf16(af, bfr[nt], acc[mt][nt], 0, 0, 0);
            }
        }
    };

    for (int k0 = 0; k0 < K; k0 += 64) {
        __syncthreads();
        if (a32) {
            const float* A = (const float*)Ap + (size_t)(m_base + m0 + arow) * K + k0 + aq * 16;
            bf16 t16[16];
            #pragma unroll
            for (int g = 0; g < 4; ++g) {
                f32x4 v = *(const f32x4*)(A + g * 4);
                #pragma unroll
                for (int j = 0; j < 4; ++j) t16[g * 4 + j] = (bf16)v[j];
            }
            *(bf16x8*)&Ash[arow][SW(arow, aq * 2)]     = *(bf16x8*)t16;
            *(bf16x8*)&Ash[arow][SW(arow, aq * 2 + 1)] = *(bf16x8*)(t16 + 8);
        } else {
            const bf16* A = (const bf16*)Ap + (size_t)(m_base + m0 + arow) * K + k0 + aq * 16;
            *(bf16x8*)&Ash[arow][SW(arow, aq * 2)]     = ld8(A);
            *(bf16x8*)&Ash[arow][SW(arow, aq * 2 + 1)] = ld8(A + 8);
        }
        {
            int nl = tid & 127, kg = tid >> 7;
            int n = n0 + nl;
            size_t base    = whead ? ((size_t)(n >> 6) * ((size_t)K * HD) + (n & 63))
                                   : (size_t)n;
            size_t kstride = whead ? (size_t)HD : (size_t)N;
            #pragma unroll
            for (int p = 0; p < 2; ++p) {
                int grp = kg + 4 * p;
                bf16 t8[8];
                #pragma unroll
                for (int j = 0; j < 8; ++j)
                    t8[j] = (bf16)Wp[base + (size_t)(k0 + grp * 8 + j) * kstride];
                *(bf16x8*)&Wsh[nl][SW(nl, grp)] = *(bf16x8*)t8;
            }
        }
        __syncthreads();
        compute();
    }

    #pragma unroll
    for (int nt = 0; nt < 2; ++nt) {
        int n = n0 + wn * 32 + nt * 16 + c;
        float bv_ = bias[n];
        #pragma unroll
        for (int mt = 0; mt < 4; ++mt)
            #pragma unroll
            for (int r = 0; r < 4; ++r) {
                int m = m0 + wm * 64 + mt * 16 + quad * 4 + r;
                float v = acc[mt][nt][r] + bv_;
                if (cmode == 0)      ((bf16*)Cp)[(size_t)m * N + n] = (bf16)v;
                else if (cmode == 1) ((float*)Cp)[(size_t)m * N + n] = v;
                else {
                    int mm = m_base + m;
                    ((bf16*)Cp)[((size_t)((mm >> 11) * NH + (n >> 6)) * HD + (n & 63)) * S_LEN + (mm & 2047)] = (bf16)v;
                }
            }
    }
}

// ---------------------------------------------------------------------------
// Flash attention, S^T orientation. 512 thr = 8 waves x 16 q-rows, q-tile 128.
// R4-exact (best measured: 60.4us): baseline inner loop + XCD remap. FROZEN.
// ---------------------------------------------------------------------------
__global__ __launch_bounds__(512, 2)
void attn_kernel(bf16* q0p, bf16* q1p, const bf16* __restrict__ kbuf,
                 const bf16* __restrict__ VTg, const u64* __restrict__ pmask)
{
    const int tid  = threadIdx.x;
    const int w    = tid >> 6;          // 0..7
    const int lane = tid & 63;
    const int quad = lane >> 4;
    const int c    = lane & 15;
    // XCD-chunked bijective remap (gridDim = 16 x 32 = 512 blocks)
    const int flat  = blockIdx.y * 16 + blockIdx.x;
    const int flat2 = (flat & 7) * 64 + (flat >> 3);
    const int q0   = (flat2 & 15) * 128;
    const int bh   = flat2 >> 4;
    const int b    = bh >> 4, h = bh & 15;

    bf16* qc = b ? q1p : q0p;
    const bf16* kh_ = kbuf + (size_t)b * S_LEN * EMB + h * HD;
    const bf16* vt  = VTg + (size_t)bh * HD * S_LEN;

    __shared__ bf16 Ksh [2][64][64];
    __shared__ bf16 VTsh[2][64][64];
    __shared__ bf16 Psh[8][16][64];

    // Q fragments (B-operand): wave owns rows q0 + w*16 + c
    bf16x8 qf[2];
    #pragma unroll
    for (int kk = 0; kk < 2; ++kk)
        qf[kk] = ld8(qc + (size_t)(q0 + w * 16 + c) * EMB + h * HD + kk * 32 + quad * 8);

    const u64* pmr = pmask + (size_t)(b * S_LEN + q0 + w * 16 + c) * (S_LEN / 64);

    f32x4 l4 = (f32x4){0.f,0.f,0.f,0.f};
    f32x4 o[4];
    #pragma unroll
    for (int dt = 0; dt < 4; ++dt) o[dt] = (f32x4){0.f,0.f,0.f,0.f};

    const int srow = tid >> 3, sg = tid & 7;   // 64 rows x 8 groups
    bf16x8 kr, vr;
    auto loadKV = [&](int t0) {
        kr = ld8(kh_ + (size_t)(t0 + srow) * EMB + sg * 8);
        vr = ld8(vt + (size_t)srow * S_LEN + t0 + sg * 8);
    };

    loadKV(0);
    int buf = 0;
    for (int t0 = 0; t0 < S_LEN; t0 += 64) {
        *(bf16x8*)&Ksh [buf][srow][SW(srow, sg)] = kr;
        *(bf16x8*)&VTsh[buf][srow][SW(srow, sg)] = vr;
        __syncthreads();                       // single barrier per chunk (dbuf)
        if (t0 + 64 < S_LEN) loadKV(t0 + 64);

        u64 s0 = pmr[t0 >> 6] >> (quad * 4);
        u32 mm[2] = {(u32)s0, (u32)(s0 >> 32)};

        // S^T = K . Q^T
        f32x4 sc[4];
        #pragma unroll
        for (int tt = 0; tt < 4; ++tt) sc[tt] = (f32x4){0.f,0.f,0.f,0.f};
        #pragma unroll
        for (int tt = 0; tt < 4; ++tt)
            #pragma unroll
            for (int kk = 0; kk < 2; ++kk) {
                int rk = tt * 16 + c;
                bf16x8 ka = ld8(&Ksh[buf][rk][SW(rk, kk * 4 + quad)]);
                sc[tt] = __builtin_amdgcn_mfma_f32_16x16x32_bf16(ka, qf[kk], sc[tt], 0, 0, 0);
            }

        // per-lane softmax: p = mask ? exp2(s) : 0
        #pragma unroll
        for (int tt = 0; tt < 4; ++tt) {
            u32 half = mm[tt >> 1];
            bf16x4 pv;
            #pragma unroll
            for (int r = 0; r < 4; ++r) {
                float e = __builtin_amdgcn_exp2f(sc[tt][r]);
                e = ((half >> ((tt & 1) * 16 + r)) & 1) ? e : 0.f;
                l4[r] += e;
                pv[r] = (bf16)e;
            }
            *(bf16x4*)&Psh[w][c][SW(c, tt * 2 + (quad >> 1)) + (quad & 1) * 4] = pv;
        }
        __builtin_amdgcn_s_waitcnt(0xc07f);    // lgkmcnt(0) only (same-wave P)

        // O^T += V^T . P^T
        #pragma unroll
        for (int th = 0; th < 2; ++th) {
            bf16x8 pf = ld8(&Psh[w][c][SW(c, th * 4 + quad)]);
            #pragma unroll
            for (int dt = 0; dt < 4; ++dt) {
                int rv = dt * 16 + c;
                bf16x8 av = ld8(&VTsh[buf][rv][SW(rv, th * 4 + quad)]);
                o[dt] = __builtin_amdgcn_mfma_f32_16x16x32_bf16(av, pf, o[dt], 0, 0, 0);
            }
        }
        buf ^= 1;
    }

    // epilogue: reduce l across quads (lanes sharing s=c), normalize, write
    float ls = l4[0] + l4[1] + l4[2] + l4[3];
    ls += __shfl_xor(ls, 16);
    ls += __shfl_xor(ls, 32);
    float inv = 1.0f / fmaxf(ls, 1e-30f);
    #pragma unroll
    for (int dt = 0; dt < 4; ++dt) {
        bf16x4 ov;
        #pragma unroll
        for (int r = 0; r < 4; ++r) ov[r] = (bf16)(o[dt][r] * inv);
        *(bf16x4*)&qc[(size_t)(q0 + w * 16 + c) * EMB + h * HD + dt * 16 + quad * 4] = ov;
    }
}

// ---------------------------------------------------------------------------
// d_out: V^T [0:8MB) + K [8:16MB) (consumed by attn before fp32 out-proj).
// ---------------------------------------------------------------------------
extern "C" void kernel_launch(void* const* d_in, const int* in_sizes, int n_in,
                              void* d_out, int out_size, void* d_ws, size_t ws_size,
                              hipStream_t stream)
{
    const float* x    = (const float*)d_in[0];
    const int*   mask = (const int*)d_in[1];
    const float* Wq   = (const float*)d_in[2];
    const float* bq   = (const float*)d_in[3];
    const float* Wk   = (const float*)d_in[4];
    const float* bk   = (const float*)d_in[5];
    const float* Wv   = (const float*)d_in[6];
    const float* bv   = (const float*)d_in[7];
    const float* Wo   = (const float*)d_in[8];
    const float* bo   = (const float*)d_in[9];
    float* out = (float*)d_out;

    const size_t SLAB = (size_t)S_LEN * EMB;
    const size_t QB = (size_t)BS * SLAB * sizeof(bf16);          // 8 MB
    const size_t WT = (size_t)4 * EMB * EMB * sizeof(bf16);      // 8 MB
    const size_t PM = (size_t)BS * S_LEN * (S_LEN / 64) * 8;     // 1 MB
    const size_t XB = (size_t)BS * SLAB * sizeof(bf16);          // 8 MB

    bf16* VT = (bf16*)d_out;
    bf16* kb = (bf16*)d_out + BS * SLAB;

    dim3 b256(256), b512(512);
    dim3 gAtt (S_LEN / 128, BS * NH);
    dim3 gPk  (BS * S_LEN / 4);
    dim3 gFull(BS * S_LEN / 128, EMB / 128);
    dim3 gHalf(S_LEN / 128, EMB / 128);

    if (ws_size >= QB + WT + PM + XB + 64) {
        bf16* qb  = (bf16*)d_ws;
        bf16* Wt  = (bf16*)((char*)d_ws + QB);
        u64*  pm  = (u64*)((char*)d_ws + QB + WT);
        bf16* xbf = (bf16*)((char*)d_ws + QB + WT + PM);

        prep<<<dim3(3072), b256, 0, stream>>>(x, xbf, mask, pm, Wq, Wk, Wv, Wo, Wt);

        gemm_qkv<<<dim3(BS * S_LEN / 128, 3 * EMB / 128), b256, 0, stream>>>(
            xbf, Wt, bq, bk, bv, qb, kb, VT, 0);

        attn_kernel<<<gAtt, b512, 0, stream>>>(qb, qb + SLAB, kb, VT, pm);

        gemm_o<<<dim3(BS * S_LEN / 128, EMB / 64), b256, 0, stream>>>(
            qb, Wt + (size_t)3 * EMB * EMB, bo, out);
    } else if (ws_size >= QB + PM + 64) {
        bf16* qb = (bf16*)d_ws;
        u64*  pm = (u64*)((char*)d_ws + QB);
        pack_mask<<<gPk, b256, 0, stream>>>(mask, pm);

        gemm128<<<gFull, b512, 0, stream>>>(x, Wk, nullptr, bk, kb, EMB, EMB, 1, 0, 1, 0);
        gemm128<<<gFull, b512, 0, stream>>>(x, Wv, nullptr, bv, VT, EMB, EMB, 1, 0, 1, 2);
        gemm128<<<gFull, b512, 0, stream>>>(x, Wq, nullptr, bq, qb, EMB, EMB, 1, 0, 1, 0);
        scale_q<<<dim3(BS * SLAB / (256 * 8)), b256, 0, stream>>>(qb);

        attn_kernel<<<gAtt, b512, 0, stream>>>(qb, qb + SLAB, kb, VT, pm);

        gemm128<<<gFull, b512, 0, stream>>>(qb, Wo, nullptr, bo, out, EMB, EMB, 0, 0, 0, 1);
    } else {
        bf16* qb0 = (bf16*)d_in[4];
        bf16* qb1 = (bf16*)d_in[6];
        u64*  pm  = (u64*)d_in[2];

        gemm128<<<gFull, b512, 0, stream>>>(x, Wk, nullptr, bk, kb, EMB, EMB, 1, 0, 1, 0);
        gemm128<<<gFull, b512, 0, stream>>>(x, Wv, nullptr, bv, VT, EMB, EMB, 1, 0, 1, 2);
        gemm128<<<gHalf, b512, 0, stream>>>(x, Wq, nullptr, bq, qb0, EMB, EMB, 1, 0,     1, 0);
        gemm128<<<gHalf, b512, 0, stream>>>(x, Wq, nullptr, bq, qb1, EMB, EMB, 1, S_LEN, 1, 0);
        scale_q<<<dim3(SLAB / (256 * 8)), b256, 0, stream>>>(qb0);
        scale_q<<<dim3(SLAB / (256 * 8)), b256, 0, stream>>>(qb1);
        pack_mask<<<gPk, b256, 0, stream>>>(mask, pm);

        attn_kernel<<<gAtt, b512, 0, stream>>>(qb0, qb1, kb, VT, pm);

        gemm128<<<gHalf, b512, 0, stream>>>(qb0, Wo, nullptr, bo, out,        EMB, EMB, 0, 0, 0, 1);
        gemm128<<<gHalf, b512, 0, stream>>>(qb1, Wo, nullptr, bo, out + SLAB, EMB, EMB, 0, 0, 0, 1);
    }
}